// Round 13
// baseline (113.494 us; speedup 1.0000x reference)
//
#include <hip/hip_runtime.h>
#include <math.h>

#define NB 8
#define SEQ 256
#define DIMC 512
#define NHEAD 8
#define DHEAD 64
#define SCALEF 0.125f

typedef __attribute__((ext_vector_type(8))) short s16x8;
typedef __attribute__((ext_vector_type(4))) float f32x4;

typedef __attribute__((address_space(3))) unsigned int lds_u32_t;
typedef const __attribute__((address_space(1))) unsigned int g_u32_t;
static __device__ __forceinline__ void gl_lds16(const void* gsrc, void* ldst) {
  __builtin_amdgcn_global_load_lds((g_u32_t*)gsrc, (lds_u32_t*)ldst, 16, 0, 0);
}

static __device__ __forceinline__ unsigned short f2bf(float f) {
  union { float f; unsigned u; } c; c.f = f;
  unsigned r = c.u + 0x7FFF + ((c.u >> 16) & 1);  // RNE
  return (unsigned short)(r >> 16);
}
static __device__ __forceinline__ float bf2f(unsigned short u) {
  union { unsigned u; float f; } c; c.u = ((unsigned)u) << 16;
  return c.f;
}

// ---------------- K0: fused prep: tcast(w_qkv), tcast(w_out), up->bf16, LN ---
static __device__ void tcast_body(const float* __restrict__ W,
    unsigned short* __restrict__ WT, int K, int N, int n0, int k0, int t,
    float (*tile)[65]) {
#pragma unroll
  for (int i = 0; i < 16; ++i) {
    const int idx = i * 256 + t;
    const int kl = idx >> 6, nl = idx & 63;
    tile[kl][nl] = W[(size_t)(k0 + kl) * N + n0 + nl];
  }
  __syncthreads();
#pragma unroll
  for (int i = 0; i < 16; ++i) {
    const int idx = i * 256 + t;
    const int nl = idx >> 6, kl = idx & 63;
    WT[(size_t)(n0 + nl) * K + k0 + kl] = f2bf(tile[kl][nl]);
  }
}

__global__ __launch_bounds__(256) void prep_kernel(const float* __restrict__ x,
    const float* __restrict__ g, const float* __restrict__ bta,
    const float* __restrict__ w_qkv, const float* __restrict__ w_out,
    const float* __restrict__ up, unsigned short* __restrict__ xnb,
    unsigned short* __restrict__ wqt, unsigned short* __restrict__ wot,
    unsigned short* __restrict__ upb) {
  __shared__ float tile[64][65];
  __shared__ float sh_s[4], sh_q[4];
  const int t = threadIdx.x;
  const int bid = blockIdx.x;
  if (bid < 192) {
    tcast_body(w_qkv, wqt, 512, 1536, (bid % 24) * 64, (bid / 24) * 64, t, tile);
  } else if (bid < 256) {
    const int b2 = bid - 192;
    tcast_body(w_out, wot, 512, 512, (b2 % 8) * 64, (b2 / 8) * 64, t, tile);
  } else if (bid < 497) {
    const int base = (bid - 256) * 2048 + t * 4;
#pragma unroll
    for (int it = 0; it < 2; ++it) {
      const int i = base + it * 1024;
      if (i < 492032) {
        const float4 v = *(const float4*)&up[i];
        ushort4 w;
        w.x = f2bf(v.x); w.y = f2bf(v.y); w.z = f2bf(v.z); w.w = f2bf(v.w);
        *(ushort4*)&upb[i] = w;
      }
    }
  } else {
    const int row = bid - 497;
    const float2 v = ((const float2*)(x + (size_t)row * DIMC))[t];
    float s = v.x + v.y;
    float q = v.x * v.x + v.y * v.y;
#pragma unroll
    for (int off = 32; off > 0; off >>= 1) {
      s += __shfl_down(s, off);
      q += __shfl_down(q, off);
    }
    const int wave = t >> 6, lane = t & 63;
    if (lane == 0) { sh_s[wave] = s; sh_q[wave] = q; }
    __syncthreads();
    const float fs = sh_s[0] + sh_s[1] + sh_s[2] + sh_s[3];
    const float fq = sh_q[0] + sh_q[1] + sh_q[2] + sh_q[3];
    const float mean = fs * (1.0f / DIMC);
    const float inv = rsqrtf(fq * (1.0f / DIMC) - mean * mean + 1e-5f);
    const float2 gv = ((const float2*)g)[t];
    const float2 bv = ((const float2*)bta)[t];
    ushort2 o;
    o.x = f2bf((v.x - mean) * inv * gv.x + bv.x);
    o.y = f2bf((v.y - mean) * inv * gv.y + bv.y);
    ((ushort2*)(xnb + (size_t)row * DIMC))[t] = o;
  }
}

// ---------------- bf16 MFMA GEMM: C = A(MxK) @ BT(NxK)^T (+bias) -------------
template <int BM, int BN, bool BIAS, bool OUTBF, bool VSPLIT>
__global__ __launch_bounds__(256) void mfma_gemm_bt(
    const unsigned short* __restrict__ A, const unsigned short* __restrict__ BT,
    const float* __restrict__ bias, void* __restrict__ Cv,
    unsigned short* __restrict__ vtb, int M, int K, int N) {
  constexpr int TR = BM / 32;
  constexpr int TC = BN / 32;
  __shared__ unsigned short As[BM * 32];
  __shared__ unsigned short Bs[BN * 32];
  const int t = threadIdx.x;
  const int wave = t >> 6, lane = t & 63;
  const int wr = wave >> 1, wc = wave & 1;
  const int bm = blockIdx.x * BM, bn = blockIdx.y * BN;

  f32x4 acc[TR][TC] = {};

  const int fr = lane & 15, q4 = lane >> 4;
  const int kBlocks = K >> 5;
  for (int kb = 0; kb < kBlocks; ++kb) {
    const int k0 = kb << 5;
    __syncthreads();
#pragma unroll
    for (int c = 0; c < (BM * 4 + 255) / 256; ++c) {
      const int p = c * 256 + t;
      if (BM * 4 % 256 == 0 || p < BM * 4) {
        const int row = p >> 2;
        const int jl = (p & 3) ^ ((row >> 1) & 3);
        gl_lds16(A + (size_t)(bm + row) * K + k0 + jl * 8,
                 As + (size_t)(c * 256 + wave * 64) * 8);
      }
    }
#pragma unroll
    for (int c = 0; c < (BN * 4 + 255) / 256; ++c) {
      const int p = c * 256 + t;
      if (BN * 4 % 256 == 0 || p < BN * 4) {
        const int row = p >> 2;
        const int jl = (p & 3) ^ ((row >> 1) & 3);
        gl_lds16(BT + (size_t)(bn + row) * K + k0 + jl * 8,
                 Bs + (size_t)(c * 256 + wave * 64) * 8);
      }
    }
    __syncthreads();
    s16x8 af[TR], bfr[TC];
#pragma unroll
    for (int i = 0; i < TR; ++i) {
      const int row = wr * (BM / 2) + i * 16 + fr;
      const int jp = q4 ^ ((row >> 1) & 3);
      af[i] = *(const s16x8*)(As + row * 32 + jp * 8);
    }
#pragma unroll
    for (int j = 0; j < TC; ++j) {
      const int row = wc * (BN / 2) + j * 16 + fr;
      const int jp = q4 ^ ((row >> 1) & 3);
      bfr[j] = *(const s16x8*)(Bs + row * 32 + jp * 8);
    }
#pragma unroll
    for (int i = 0; i < TR; ++i)
#pragma unroll
      for (int j = 0; j < TC; ++j)
        acc[i][j] = __builtin_amdgcn_mfma_f32_16x16x32_bf16(af[i], bfr[j],
                                                            acc[i][j], 0, 0, 0);
  }
  if (VSPLIT && bn >= 1024) {
#pragma unroll
    for (int i = 0; i < TR; ++i) {
#pragma unroll
      for (int j = 0; j < TC; ++j) {
        const int hc = bn - 1024 + wc * (BN / 2) + j * 16 + fr;
        const int h = hc >> 6, d = hc & 63;
#pragma unroll
        for (int r = 0; r < 4; ++r) {
          const int row = bm + wr * (BM / 2) + i * 16 + q4 * 4 + r;
          const int b = row >> 8, m = row & 255;
          vtb[(size_t)((b * 8 + h) * 64 + d) * 256 + m] = f2bf(acc[i][j][r]);
        }
      }
    }
    return;
  }
#pragma unroll
  for (int i = 0; i < TR; ++i) {
#pragma unroll
    for (int j = 0; j < TC; ++j) {
      const int col = bn + wc * (BN / 2) + j * 16 + fr;
      const float bv = BIAS ? bias[col] : 0.0f;
#pragma unroll
      for (int r = 0; r < 4; ++r) {
        const int row = bm + wr * (BM / 2) + i * 16 + q4 * 4 + r;
        if constexpr (OUTBF) {
          ((unsigned short*)Cv)[(size_t)row * N + col] = f2bf(acc[i][j][r] + bv);
        } else {
          ((float*)Cv)[(size_t)row * N + col] = acc[i][j][r] + bv;
        }
      }
    }
  }
}

// ---------------- K3: fused QK^T -> softmax -> AV, 128 thr / 32 n-rows -------
// K staged [m][64] stride-64, V^T staged [d][256] stride-256, both via
// global_load_lds(16B) with XOR chunk swizzle (phys chunk c holds logical
// c^(row&7)); frag ds_read_b128 bank pattern is 2-way max (free).
#define PSTR 264
__global__ __launch_bounds__(128) void fused_attn_kernel(
    const unsigned short* __restrict__ qkvb, const unsigned short* __restrict__ vtb,
    unsigned short* __restrict__ attnb, unsigned short* __restrict__ oav) {
  __shared__ unsigned short kv_lds[256 * 64];   // 32 KB: K stage, then V^T
  __shared__ unsigned short p_lds[32 * PSTR];   // 16.5 KB
  const int bh = blockIdx.y, b = bh >> 3, h = bh & 7;
  const int n0 = blockIdx.x * 32;
  const int t = threadIdx.x, wave = t >> 6, lane = t & 63;
  const int fr = lane & 15, q4 = lane >> 4;

  // stage K[m][64] via gl_lds16: 2048 chunks / 128 thr, swizzled source
#pragma unroll
  for (int p = 0; p < 16; ++p) {
    const int l = p * 128 + t;
    const int m = l >> 3, c = l & 7;
    const int jl = c ^ (m & 7);
    gl_lds16(qkvb + (size_t)(b * SEQ + m) * 1536 + 512 + h * 64 + jl * 8,
             kv_lds + (size_t)(p * 128 + wave * 64) * 8);
  }
  s16x8 qf[2];
  {
    const size_t qrow = (size_t)(b * SEQ + n0 + wave * 16 + fr) * 1536 + h * 64;
#pragma unroll
    for (int ks = 0; ks < 2; ++ks)
      qf[ks] = *(const s16x8*)(qkvb + qrow + ks * 32 + q4 * 8);
  }
  __syncthreads();

  f32x4 s[16];
#pragma unroll
  for (int mt = 0; mt < 16; ++mt) s[mt] = (f32x4){0.f, 0.f, 0.f, 0.f};
#pragma unroll
  for (int ks = 0; ks < 2; ++ks)
#pragma unroll
    for (int mt = 0; mt < 16; ++mt) {
      const int m = mt * 16 + fr;
      const int jp = (ks * 4 + q4) ^ (m & 7);
      const s16x8 kf = *(const s16x8*)(kv_lds + m * 64 + jp * 8);
      s[mt] = __builtin_amdgcn_mfma_f32_16x16x32_bf16(qf[ks], kf, s[mt], 0, 0, 0);
    }

  float mx[4] = {-1e30f, -1e30f, -1e30f, -1e30f};
#pragma unroll
  for (int mt = 0; mt < 16; ++mt)
#pragma unroll
    for (int r = 0; r < 4; ++r) {
      s[mt][r] *= SCALEF;
      mx[r] = fmaxf(mx[r], s[mt][r]);
    }
#pragma unroll
  for (int r = 0; r < 4; ++r) {
    mx[r] = fmaxf(mx[r], __shfl_xor(mx[r], 1));
    mx[r] = fmaxf(mx[r], __shfl_xor(mx[r], 2));
    mx[r] = fmaxf(mx[r], __shfl_xor(mx[r], 4));
    mx[r] = fmaxf(mx[r], __shfl_xor(mx[r], 8));
  }
  float sum[4] = {0.f, 0.f, 0.f, 0.f};
#pragma unroll
  for (int mt = 0; mt < 16; ++mt)
#pragma unroll
    for (int r = 0; r < 4; ++r) {
      s[mt][r] = __expf(s[mt][r] - mx[r]);
      sum[r] += s[mt][r];
    }
#pragma unroll
  for (int r = 0; r < 4; ++r) {
    sum[r] += __shfl_xor(sum[r], 1);
    sum[r] += __shfl_xor(sum[r], 2);
    sum[r] += __shfl_xor(sum[r], 4);
    sum[r] += __shfl_xor(sum[r], 8);
  }
  const float invs[4] = {1.0f / sum[0], 1.0f / sum[1], 1.0f / sum[2],
                         1.0f / sum[3]};

  __syncthreads();  // waves done with K before V^T overwrites kv_lds

  // P -> p_lds (scalar, from softmax regs); V^T -> kv_lds via gl_lds16
  {
    const int nb = wave * 16 + q4 * 4;
#pragma unroll
    for (int mt = 0; mt < 16; ++mt)
#pragma unroll
      for (int r = 0; r < 4; ++r)
        p_lds[(nb + r) * PSTR + mt * 16 + fr] = f2bf(s[mt][r] * invs[r]);
  }
#pragma unroll
  for (int p = 0; p < 16; ++p) {
    const int l = p * 128 + t;
    const int d = l >> 5, c = l & 31;
    const int jl = c ^ (d & 7);
    gl_lds16(vtb + (size_t)(bh * 64 + d) * 256 + jl * 8,
             kv_lds + (size_t)(p * 128 + wave * 64) * 8);
  }
  __syncthreads();

  // copy P -> global attn (bf16) for the rpos kernel
#pragma unroll
  for (int p = 0; p < 8; ++p) {
    const int idx = p * 128 + t;
    const int row = idx >> 5, mc = (idx & 31) * 8;
    *(s16x8*)(attnb + (size_t)(bh * SEQ + n0 + row) * SEQ + mc) =
        *(const s16x8*)(p_lds + row * PSTR + mc);
  }

  f32x4 o[4];
#pragma unroll
  for (int dt = 0; dt < 4; ++dt) o[dt] = (f32x4){0.f, 0.f, 0.f, 0.f};
#pragma unroll
  for (int ks = 0; ks < 8; ++ks) {
    const s16x8 pf =
        *(const s16x8*)(p_lds + (wave * 16 + fr) * PSTR + ks * 32 + q4 * 8);
#pragma unroll
    for (int dt = 0; dt < 4; ++dt) {
      const int d = dt * 16 + fr;
      const int jp = (ks * 4 + q4) ^ (d & 7);
      const s16x8 vf = *(const s16x8*)(kv_lds + d * 256 + jp * 8);
      o[dt] = __builtin_amdgcn_mfma_f32_16x16x32_bf16(pf, vf, o[dt], 0, 0, 0);
    }
  }
#pragma unroll
  for (int dt = 0; dt < 4; ++dt)
#pragma unroll
    for (int r = 0; r < 4; ++r) {
      const int n = n0 + wave * 16 + q4 * 4 + r;
      oav[(size_t)(b * SEQ + n) * DIMC + h * 64 + dt * 16 + fr] = f2bf(o[dt][r]);
    }
}

// ---------------- K4: rpos as MFMA GEMM, block per (n,h) ---------------------
#define USTR 264
#define ASTR2 264
__global__ __launch_bounds__(256) void rpos_kernel(
    const unsigned short* __restrict__ attnb, const unsigned short* __restrict__ upb,
    unsigned short* __restrict__ ob) {
  __shared__ unsigned short upT[64 * USTR];   // 33,792 B
  __shared__ unsigned short aS[16 * ASTR2];   //  8,448 B (rows 8-15 unused)
  const int t = threadIdx.x, wave = t >> 6, lane = t & 63;
  const int fr = lane & 15, q4 = lane >> 4;
  const int task = blockIdx.x;                // 2048 = 256 n x 8 h
  const int n = task >> 3, h = task & 7;
  const int xn = n >> 4, yn = n & 15;

  {
    const int b = t >> 5, mc = (t & 31) * 8;
    *(s16x8*)(aS + b * ASTR2 + mc) =
        *(const s16x8*)(attnb + (size_t)((b * 8 + h) * SEQ + n) * SEQ + mc);
  }
#pragma unroll
  for (int i = 0; i < 8; ++i) {
    const int chunk = i * 256 + t;
    const int m = chunk >> 3;
    const int g8 = chunk & 7;
    const int xm = m >> 4, ym = m & 15;
    const int row = (xn - xm + 15) * 31 + (yn - ym + 15);
    const s16x8 v = *(const s16x8*)(upb + (size_t)row * DIMC + h * 64 + g8 * 8);
    const int mc_phys = ((m >> 3) ^ g8) * 8 + (m & 7);
#pragma unroll
    for (int j = 0; j < 8; ++j)
      upT[(g8 * 8 + j) * USTR + mc_phys] = (unsigned short)v[j];
  }
  __syncthreads();

  f32x4 acc = (f32x4){0.f, 0.f, 0.f, 0.f};
  const int d = wave * 16 + fr;
#pragma unroll
  for (int ks = 0; ks < 8; ++ks) {
    const s16x8 af = *(const s16x8*)(aS + fr * ASTR2 + ks * 32 + q4 * 8);
    const int c_phys = (ks * 4 + q4) ^ (d >> 3);
    const s16x8 bf = *(const s16x8*)(upT + d * USTR + c_phys * 8);
    acc = __builtin_amdgcn_mfma_f32_16x16x32_bf16(af, bf, acc, 0, 0, 0);
  }
  if (q4 < 2) {
#pragma unroll
    for (int r = 0; r < 4; ++r) {
      const int b = q4 * 4 + r;
      unsigned short* p = ob + (size_t)(b * SEQ + n) * DIMC + h * 64 + d;
      *p = f2bf(bf2f(*p) + acc[r]);
    }
  }
}

extern "C" void kernel_launch(void* const* d_in, const int* in_sizes, int n_in,
                              void* d_out, int out_size, void* d_ws,
                              size_t ws_size, hipStream_t stream) {
  const float* x = (const float*)d_in[0];
  const float* ln_g = (const float*)d_in[1];
  const float* ln_b = (const float*)d_in[2];
  const float* w_qkv = (const float*)d_in[3];
  const float* up = (const float*)d_in[4];
  const float* w_out = (const float*)d_in[5];
  const float* b_out = (const float*)d_in[6];
  float* out = (float*)d_out;

  unsigned short* u = (unsigned short*)d_ws;
  unsigned short* qkvb = u;                  // 3,145,728 (V third unused)
  unsigned short* attnb = u + 3145728;       // 4,194,304
  unsigned short* xnb = u + 7340032;         // 1,048,576
  unsigned short* ob = u + 8388608;          // 1,048,576
  unsigned short* wqt = u + 9437184;         //   786,432
  unsigned short* wot = u + 10223616;        //   262,144
  unsigned short* upb = u + 10485760;        //   492,032
  unsigned short* vtb = u + 10977792;        // 1,048,576
  if (ws_size < (size_t)12026368 * sizeof(unsigned short)) return;  // ~24 MB

  prep_kernel<<<2545, 256, 0, stream>>>(x, ln_g, ln_b, w_qkv, w_out, up,
                                        xnb, wqt, wot, upb);
  mfma_gemm_bt<64, 64, false, true, true>
      <<<dim3(32, 24), 256, 0, stream>>>(xnb, wqt, nullptr, qkvb, vtb,
                                         2048, 512, 1536);
  fused_attn_kernel<<<dim3(8, 64), 128, 0, stream>>>(qkvb, vtb, attnb, ob);
  rpos_kernel<<<2048, 256, 0, stream>>>(attnb, upb, ob);
  mfma_gemm_bt<64, 32, true, false, false>
      <<<dim3(32, 16), 256, 0, stream>>>(ob, wot, b_out, out, nullptr,
                                         2048, 512, 512);
}

// Round 14
// 112.670 us; speedup vs baseline: 1.0073x; 1.0073x over previous
//
#include <hip/hip_runtime.h>
#include <math.h>

#define NB 8
#define SEQ 256
#define DIMC 512
#define NHEAD 8
#define DHEAD 64
#define SCALEF 0.125f

typedef __attribute__((ext_vector_type(8))) short s16x8;
typedef __attribute__((ext_vector_type(4))) float f32x4;

typedef __attribute__((address_space(3))) unsigned int lds_u32_t;
typedef const __attribute__((address_space(1))) unsigned int g_u32_t;
static __device__ __forceinline__ void gl_lds16(const void* gsrc, void* ldst) {
  __builtin_amdgcn_global_load_lds((g_u32_t*)gsrc, (lds_u32_t*)ldst, 16, 0, 0);
}

static __device__ __forceinline__ unsigned short f2bf(float f) {
  union { float f; unsigned u; } c; c.f = f;
  unsigned r = c.u + 0x7FFF + ((c.u >> 16) & 1);  // RNE
  return (unsigned short)(r >> 16);
}
static __device__ __forceinline__ float bf2f(unsigned short u) {
  union { unsigned u; float f; } c; c.u = ((unsigned)u) << 16;
  return c.f;
}

// ---------------- K0: fused prep: tcast(w_qkv), tcast(w_out), up->bf16, LN ---
static __device__ void tcast_body(const float* __restrict__ W,
    unsigned short* __restrict__ WT, int K, int N, int n0, int k0, int t,
    float (*tile)[65]) {
#pragma unroll
  for (int i = 0; i < 16; ++i) {
    const int idx = i * 256 + t;
    const int kl = idx >> 6, nl = idx & 63;
    tile[kl][nl] = W[(size_t)(k0 + kl) * N + n0 + nl];
  }
  __syncthreads();
#pragma unroll
  for (int i = 0; i < 16; ++i) {
    const int idx = i * 256 + t;
    const int nl = idx >> 6, kl = idx & 63;
    WT[(size_t)(n0 + nl) * K + k0 + kl] = f2bf(tile[kl][nl]);
  }
}

__global__ __launch_bounds__(256) void prep_kernel(const float* __restrict__ x,
    const float* __restrict__ g, const float* __restrict__ bta,
    const float* __restrict__ w_qkv, const float* __restrict__ w_out,
    const float* __restrict__ up, unsigned short* __restrict__ xnb,
    unsigned short* __restrict__ wqt, unsigned short* __restrict__ wot,
    unsigned short* __restrict__ upb) {
  __shared__ float tile[64][65];
  __shared__ float sh_s[4], sh_q[4];
  const int t = threadIdx.x;
  const int bid = blockIdx.x;
  if (bid < 192) {
    tcast_body(w_qkv, wqt, 512, 1536, (bid % 24) * 64, (bid / 24) * 64, t, tile);
  } else if (bid < 256) {
    const int b2 = bid - 192;
    tcast_body(w_out, wot, 512, 512, (b2 % 8) * 64, (b2 / 8) * 64, t, tile);
  } else if (bid < 497) {
    const int base = (bid - 256) * 2048 + t * 4;
#pragma unroll
    for (int it = 0; it < 2; ++it) {
      const int i = base + it * 1024;
      if (i < 492032) {
        const float4 v = *(const float4*)&up[i];
        ushort4 w;
        w.x = f2bf(v.x); w.y = f2bf(v.y); w.z = f2bf(v.z); w.w = f2bf(v.w);
        *(ushort4*)&upb[i] = w;
      }
    }
  } else {
    const int row = bid - 497;
    const float2 v = ((const float2*)(x + (size_t)row * DIMC))[t];
    float s = v.x + v.y;
    float q = v.x * v.x + v.y * v.y;
#pragma unroll
    for (int off = 32; off > 0; off >>= 1) {
      s += __shfl_down(s, off);
      q += __shfl_down(q, off);
    }
    const int wave = t >> 6, lane = t & 63;
    if (lane == 0) { sh_s[wave] = s; sh_q[wave] = q; }
    __syncthreads();
    const float fs = sh_s[0] + sh_s[1] + sh_s[2] + sh_s[3];
    const float fq = sh_q[0] + sh_q[1] + sh_q[2] + sh_q[3];
    const float mean = fs * (1.0f / DIMC);
    const float inv = rsqrtf(fq * (1.0f / DIMC) - mean * mean + 1e-5f);
    const float2 gv = ((const float2*)g)[t];
    const float2 bv = ((const float2*)bta)[t];
    ushort2 o;
    o.x = f2bf((v.x - mean) * inv * gv.x + bv.x);
    o.y = f2bf((v.y - mean) * inv * gv.y + bv.y);
    ((ushort2*)(xnb + (size_t)row * DIMC))[t] = o;
  }
}

// ---------------- bf16 MFMA GEMM: C = A(MxK) @ BT(NxK)^T (+bias) -------------
template <int BM, int BN, bool BIAS, bool OUTBF, bool VSPLIT>
__global__ __launch_bounds__(256) void mfma_gemm_bt(
    const unsigned short* __restrict__ A, const unsigned short* __restrict__ BT,
    const float* __restrict__ bias, void* __restrict__ Cv,
    unsigned short* __restrict__ vtb, int M, int K, int N) {
  constexpr int TR = BM / 32;
  constexpr int TC = BN / 32;
  __shared__ unsigned short As[BM * 32];
  __shared__ unsigned short Bs[BN * 32];
  const int t = threadIdx.x;
  const int wave = t >> 6, lane = t & 63;
  const int wr = wave >> 1, wc = wave & 1;
  const int bm = blockIdx.x * BM, bn = blockIdx.y * BN;

  f32x4 acc[TR][TC] = {};

  const int fr = lane & 15, q4 = lane >> 4;
  const int kBlocks = K >> 5;
  for (int kb = 0; kb < kBlocks; ++kb) {
    const int k0 = kb << 5;
    __syncthreads();
#pragma unroll
    for (int c = 0; c < (BM * 4 + 255) / 256; ++c) {
      const int p = c * 256 + t;
      if (BM * 4 % 256 == 0 || p < BM * 4) {
        const int row = p >> 2;
        const int jl = (p & 3) ^ ((row >> 1) & 3);
        gl_lds16(A + (size_t)(bm + row) * K + k0 + jl * 8,
                 As + (size_t)(c * 256 + wave * 64) * 8);
      }
    }
#pragma unroll
    for (int c = 0; c < (BN * 4 + 255) / 256; ++c) {
      const int p = c * 256 + t;
      if (BN * 4 % 256 == 0 || p < BN * 4) {
        const int row = p >> 2;
        const int jl = (p & 3) ^ ((row >> 1) & 3);
        gl_lds16(BT + (size_t)(bn + row) * K + k0 + jl * 8,
                 Bs + (size_t)(c * 256 + wave * 64) * 8);
      }
    }
    __syncthreads();
    s16x8 af[TR], bfr[TC];
#pragma unroll
    for (int i = 0; i < TR; ++i) {
      const int row = wr * (BM / 2) + i * 16 + fr;
      const int jp = q4 ^ ((row >> 1) & 3);
      af[i] = *(const s16x8*)(As + row * 32 + jp * 8);
    }
#pragma unroll
    for (int j = 0; j < TC; ++j) {
      const int row = wc * (BN / 2) + j * 16 + fr;
      const int jp = q4 ^ ((row >> 1) & 3);
      bfr[j] = *(const s16x8*)(Bs + row * 32 + jp * 8);
    }
#pragma unroll
    for (int i = 0; i < TR; ++i)
#pragma unroll
      for (int j = 0; j < TC; ++j)
        acc[i][j] = __builtin_amdgcn_mfma_f32_16x16x32_bf16(af[i], bfr[j],
                                                            acc[i][j], 0, 0, 0);
  }
  if (VSPLIT && bn >= 1024) {
#pragma unroll
    for (int i = 0; i < TR; ++i) {
#pragma unroll
      for (int j = 0; j < TC; ++j) {
        const int hc = bn - 1024 + wc * (BN / 2) + j * 16 + fr;
        const int h = hc >> 6, d = hc & 63;
#pragma unroll
        for (int r = 0; r < 4; ++r) {
          const int row = bm + wr * (BM / 2) + i * 16 + q4 * 4 + r;
          const int b = row >> 8, m = row & 255;
          vtb[(size_t)((b * 8 + h) * 64 + d) * 256 + m] = f2bf(acc[i][j][r]);
        }
      }
    }
    return;
  }
#pragma unroll
  for (int i = 0; i < TR; ++i) {
#pragma unroll
    for (int j = 0; j < TC; ++j) {
      const int col = bn + wc * (BN / 2) + j * 16 + fr;
      const float bv = BIAS ? bias[col] : 0.0f;
#pragma unroll
      for (int r = 0; r < 4; ++r) {
        const int row = bm + wr * (BM / 2) + i * 16 + q4 * 4 + r;
        if constexpr (OUTBF) {
          ((unsigned short*)Cv)[(size_t)row * N + col] = f2bf(acc[i][j][r] + bv);
        } else {
          ((float*)Cv)[(size_t)row * N + col] = acc[i][j][r] + bv;
        }
      }
    }
  }
}

// ---------------- K3: fused QK^T -> softmax -> AV, 128 thr / 32 n-rows -------
#define PSTR 264
#define KSTR 72
__global__ __launch_bounds__(128) void fused_attn_kernel(
    const unsigned short* __restrict__ qkvb, const unsigned short* __restrict__ vtb,
    unsigned short* __restrict__ attnb, unsigned short* __restrict__ oav) {
  __shared__ unsigned short kv_lds[256 * KSTR];  // K stage, then V^T stage
  __shared__ unsigned short p_lds[32 * PSTR];
  const int bh = blockIdx.y, b = bh >> 3, h = bh & 7;
  const int n0 = blockIdx.x * 32;
  const int t = threadIdx.x, wave = t >> 6, lane = t & 63;
  const int fr = lane & 15, q4 = lane >> 4;

#pragma unroll
  for (int p = 0; p < 16; ++p) {
    const int chunk = p * 128 + t;
    const int m = chunk >> 3, c = chunk & 7;
    *(s16x8*)(kv_lds + m * KSTR + c * 8) =
        *(const s16x8*)(qkvb + (size_t)(b * SEQ + m) * 1536 + 512 + h * 64 + c * 8);
  }
  s16x8 qf[2];
  {
    const size_t qrow = (size_t)(b * SEQ + n0 + wave * 16 + fr) * 1536 + h * 64;
#pragma unroll
    for (int ks = 0; ks < 2; ++ks)
      qf[ks] = *(const s16x8*)(qkvb + qrow + ks * 32 + q4 * 8);
  }
  __syncthreads();

  f32x4 s[16];
#pragma unroll
  for (int mt = 0; mt < 16; ++mt) s[mt] = (f32x4){0.f, 0.f, 0.f, 0.f};
#pragma unroll
  for (int ks = 0; ks < 2; ++ks)
#pragma unroll
    for (int mt = 0; mt < 16; ++mt) {
      const s16x8 kf =
          *(const s16x8*)(kv_lds + (mt * 16 + fr) * KSTR + ks * 32 + q4 * 8);
      s[mt] = __builtin_amdgcn_mfma_f32_16x16x32_bf16(qf[ks], kf, s[mt], 0, 0, 0);
    }

  float mx[4] = {-1e30f, -1e30f, -1e30f, -1e30f};
#pragma unroll
  for (int mt = 0; mt < 16; ++mt)
#pragma unroll
    for (int r = 0; r < 4; ++r) {
      s[mt][r] *= SCALEF;
      mx[r] = fmaxf(mx[r], s[mt][r]);
    }
#pragma unroll
  for (int r = 0; r < 4; ++r) {
    mx[r] = fmaxf(mx[r], __shfl_xor(mx[r], 1));
    mx[r] = fmaxf(mx[r], __shfl_xor(mx[r], 2));
    mx[r] = fmaxf(mx[r], __shfl_xor(mx[r], 4));
    mx[r] = fmaxf(mx[r], __shfl_xor(mx[r], 8));
  }
  float sum[4] = {0.f, 0.f, 0.f, 0.f};
#pragma unroll
  for (int mt = 0; mt < 16; ++mt)
#pragma unroll
    for (int r = 0; r < 4; ++r) {
      s[mt][r] = __expf(s[mt][r] - mx[r]);
      sum[r] += s[mt][r];
    }
#pragma unroll
  for (int r = 0; r < 4; ++r) {
    sum[r] += __shfl_xor(sum[r], 1);
    sum[r] += __shfl_xor(sum[r], 2);
    sum[r] += __shfl_xor(sum[r], 4);
    sum[r] += __shfl_xor(sum[r], 8);
  }
  const float invs[4] = {1.0f / sum[0], 1.0f / sum[1], 1.0f / sum[2],
                         1.0f / sum[3]};

  __syncthreads();  // waves done with K before V^T overwrites kv_lds

  {
    const int nb = wave * 16 + q4 * 4;
#pragma unroll
    for (int mt = 0; mt < 16; ++mt)
#pragma unroll
      for (int r = 0; r < 4; ++r)
        p_lds[(nb + r) * PSTR + mt * 16 + fr] = f2bf(s[mt][r] * invs[r]);
  }
#pragma unroll
  for (int p = 0; p < 16; ++p) {
    const int idx = p * 128 + t;
    const int d = idx >> 5, c = idx & 31;
    *(s16x8*)(kv_lds + d * PSTR + c * 8) =
        *(const s16x8*)(vtb + (size_t)(bh * 64 + d) * 256 + c * 8);
  }
  __syncthreads();

#pragma unroll
  for (int p = 0; p < 8; ++p) {
    const int idx = p * 128 + t;
    const int row = idx >> 5, mc = (idx & 31) * 8;
    *(s16x8*)(attnb + (size_t)(bh * SEQ + n0 + row) * SEQ + mc) =
        *(const s16x8*)(p_lds + row * PSTR + mc);
  }

  f32x4 o[4];
#pragma unroll
  for (int dt = 0; dt < 4; ++dt) o[dt] = (f32x4){0.f, 0.f, 0.f, 0.f};
#pragma unroll
  for (int ks = 0; ks < 8; ++ks) {
    const s16x8 pf =
        *(const s16x8*)(p_lds + (wave * 16 + fr) * PSTR + ks * 32 + q4 * 8);
#pragma unroll
    for (int dt = 0; dt < 4; ++dt) {
      const s16x8 vf =
          *(const s16x8*)(kv_lds + (dt * 16 + fr) * PSTR + ks * 32 + q4 * 8);
      o[dt] = __builtin_amdgcn_mfma_f32_16x16x32_bf16(pf, vf, o[dt], 0, 0, 0);
    }
  }
#pragma unroll
  for (int dt = 0; dt < 4; ++dt)
#pragma unroll
    for (int r = 0; r < 4; ++r) {
      const int n = n0 + wave * 16 + q4 * 4 + r;
      oav[(size_t)(b * SEQ + n) * DIMC + h * 64 + dt * 16 + fr] = f2bf(o[dt][r]);
    }
}

// ---------------- K4: rpos as MFMA GEMM, block per (n,h) ---------------------
#define USTR 264
#define ASTR2 264
__global__ __launch_bounds__(256) void rpos_kernel(
    const unsigned short* __restrict__ attnb, const unsigned short* __restrict__ upb,
    unsigned short* __restrict__ ob) {
  __shared__ unsigned short upT[64 * USTR];   // 33,792 B
  __shared__ unsigned short aS[16 * ASTR2];   //  8,448 B (rows 8-15 unused)
  const int t = threadIdx.x, wave = t >> 6, lane = t & 63;
  const int fr = lane & 15, q4 = lane >> 4;
  const int task = blockIdx.x;                // 2048 = 256 n x 8 h
  const int n = task >> 3, h = task & 7;
  const int xn = n >> 4, yn = n & 15;

  {
    const int b = t >> 5, mc = (t & 31) * 8;
    *(s16x8*)(aS + b * ASTR2 + mc) =
        *(const s16x8*)(attnb + (size_t)((b * 8 + h) * SEQ + n) * SEQ + mc);
  }
#pragma unroll
  for (int i = 0; i < 8; ++i) {
    const int chunk = i * 256 + t;
    const int m = chunk >> 3;
    const int g8 = chunk & 7;
    const int xm = m >> 4, ym = m & 15;
    const int row = (xn - xm + 15) * 31 + (yn - ym + 15);
    const s16x8 v = *(const s16x8*)(upb + (size_t)row * DIMC + h * 64 + g8 * 8);
    const int mc_phys = ((m >> 3) ^ g8) * 8 + (m & 7);
#pragma unroll
    for (int j = 0; j < 8; ++j)
      upT[(g8 * 8 + j) * USTR + mc_phys] = (unsigned short)v[j];
  }
  __syncthreads();

  f32x4 acc = (f32x4){0.f, 0.f, 0.f, 0.f};
  const int d = wave * 16 + fr;
#pragma unroll
  for (int ks = 0; ks < 8; ++ks) {
    const s16x8 af = *(const s16x8*)(aS + fr * ASTR2 + ks * 32 + q4 * 8);
    const int c_phys = (ks * 4 + q4) ^ (d >> 3);
    const s16x8 bf = *(const s16x8*)(upT + d * USTR + c_phys * 8);
    acc = __builtin_amdgcn_mfma_f32_16x16x32_bf16(af, bf, acc, 0, 0, 0);
  }
  if (q4 < 2) {
#pragma unroll
    for (int r = 0; r < 4; ++r) {
      const int b = q4 * 4 + r;
      unsigned short* p = ob + (size_t)(b * SEQ + n) * DIMC + h * 64 + d;
      *p = f2bf(bf2f(*p) + acc[r]);
    }
  }
}

extern "C" void kernel_launch(void* const* d_in, const int* in_sizes, int n_in,
                              void* d_out, int out_size, void* d_ws,
                              size_t ws_size, hipStream_t stream) {
  const float* x = (const float*)d_in[0];
  const float* ln_g = (const float*)d_in[1];
  const float* ln_b = (const float*)d_in[2];
  const float* w_qkv = (const float*)d_in[3];
  const float* up = (const float*)d_in[4];
  const float* w_out = (const float*)d_in[5];
  const float* b_out = (const float*)d_in[6];
  float* out = (float*)d_out;

  unsigned short* u = (unsigned short*)d_ws;
  unsigned short* qkvb = u;                  // 3,145,728 (V third unused)
  unsigned short* attnb = u + 3145728;       // 4,194,304
  unsigned short* xnb = u + 7340032;         // 1,048,576
  unsigned short* ob = u + 8388608;          // 1,048,576
  unsigned short* wqt = u + 9437184;         //   786,432
  unsigned short* wot = u + 10223616;        //   262,144
  unsigned short* upb = u + 10485760;        //   492,032
  unsigned short* vtb = u + 10977792;        // 1,048,576
  if (ws_size < (size_t)12026368 * sizeof(unsigned short)) return;  // ~24 MB

  prep_kernel<<<2545, 256, 0, stream>>>(x, ln_g, ln_b, w_qkv, w_out, up,
                                        xnb, wqt, wot, upb);
  mfma_gemm_bt<64, 64, false, true, true>
      <<<dim3(32, 24), 256, 0, stream>>>(xnb, wqt, nullptr, qkvb, vtb,
                                         2048, 512, 1536);
  fused_attn_kernel<<<dim3(8, 64), 128, 0, stream>>>(qkvb, vtb, attnb, ob);
  rpos_kernel<<<2048, 256, 0, stream>>>(attnb, upb, ob);
  mfma_gemm_bt<64, 32, true, false, false>
      <<<dim3(32, 16), 256, 0, stream>>>(ob, wot, b_out, out, nullptr,
                                         2048, 512, 512);
}